// Round 4
// baseline (519.797 us; speedup 1.0000x reference)
//
#include <hip/hip_runtime.h>
#include <stdint.h>
#include <math.h>

// QLoRA linear: out = x @ (scale*qweight^T) + bias + (x@A)@B
// M=8192, N=4096, K=4096, RANK=16.
//
// R4: "flatmm" restructure. prep writes x_i8 and w_i8 in MFMA *fragment*
// order, so the main GEMM K-loop is pure global_load_dwordx4 -> MFMA with
// NO LDS and NO barriers (kills the s_waitcnt vmcnt(0)+s_barrier drain that
// caps the m97-style structure at ~35% MfmaUtil).
//
// Fragment layout (matches the verified R3 LDS read pattern):
//   slab(b, k0, w, i) = ((b*64 + k0)*2 + w)*4 + i   (1024 B per slab)
//   byte addr = slab*1024 + lane*16
//   lane L of frag i holds row (b*128 + w*64 + i*16 + (L&15)),
//   k bytes k0*64 + (L>>4)*16 .. +15.

static constexpr int Mdim = 8192;
static constexpr int Ndim = 4096;
static constexpr int Kdim = 4096;

typedef __bf16 bf16x8 __attribute__((ext_vector_type(8)));
typedef float f32x4 __attribute__((ext_vector_type(4)));
typedef int   i32x4 __attribute__((ext_vector_type(4)));

__device__ __forceinline__ void async_copy16(const void* gptr, void* lptr) {
    auto g = (const __attribute__((address_space(1))) unsigned char*)(uintptr_t)gptr;
    auto l = (__attribute__((address_space(3))) unsigned char*)(uintptr_t)lptr;
    __builtin_amdgcn_global_load_lds(g, l, 16, 0, 0);
}

// ---------------- prep: roles by blockIdx ----------------
// role X [0,512):    16 x-rows/block -> per-row absmax, int8 quant, frag layout
// role W [512,768):  16 qw-rows/block -> int8, frag layout
// role A {768}:      lora_A -> per-tensor int8, B-operand frag layout [16][K]
// role Bt [769,785): lora_B [16][N] -> bf16 Blbt[N][16]
static constexpr int BLK_X = Mdim / 16;   // 512
static constexpr int BLK_W = Ndim / 16;   // 256
static constexpr int BLK_BT = Ndim / 256; // 16

__global__ void __launch_bounds__(256) prep_kernel(
        const float* __restrict__ x,
        const int* __restrict__ qw,
        const float* __restrict__ lA,   // [K][16]
        const float* __restrict__ lB,   // [16][N]
        int8_t* __restrict__ Xs,        // frag-layout x_i8
        int8_t* __restrict__ Bs,        // frag-layout w_i8
        int8_t* __restrict__ a_i8,      // frag-layout lora_A (64 KB)
        __bf16* __restrict__ Blbt,      // [N][16]
        float* __restrict__ row_scale,  // [M]
        float* __restrict__ a_scale_g) {
    __shared__ float red[8];
    int b = blockIdx.x;
    const int tid = threadIdx.x;

    if (b < BLK_X) {
        // ---- role X ----
        const int m0 = b * 16;
        const int r = tid >> 4, u = tid & 15;
        const float4* xrow4 = (const float4*)(x + (size_t)(m0 + r) * Kdim + u * 256);
        // pass 1: absmax over this thread's 256 contiguous floats
        float am = 0.f;
        for (int q = 0; q < 64; ++q) {
            float4 v = xrow4[q];
            am = fmaxf(am, fmaxf(fmaxf(fabsf(v.x), fabsf(v.y)),
                                 fmaxf(fabsf(v.z), fabsf(v.w))));
        }
#pragma unroll
        for (int off = 1; off < 16; off <<= 1) am = fmaxf(am, __shfl_xor(am, off, 16));
        if (u == 0) row_scale[m0 + r] = am > 0.f ? am / 127.f : 0.f;
        const float inv = am > 0.f ? 127.f / am : 0.f;
        // pass 2: quantize + scatter to fragment layout (re-read hits L2)
        const int bm = b >> 3, wm = (b >> 2) & 1, islab = b & 3;
#pragma unroll 4
        for (int j = 0; j < 16; ++j) {
            const int c = u * 16 + j;          // global 16-elem k-chunk
            const int k0 = c >> 2, quad = c & 3;
            int8_t o[16];
#pragma unroll
            for (int p = 0; p < 4; ++p) {
                float4 v = xrow4[j * 4 + p];
                o[p * 4 + 0] = (int8_t)(int)rintf(v.x * inv);
                o[p * 4 + 1] = (int8_t)(int)rintf(v.y * inv);
                o[p * 4 + 2] = (int8_t)(int)rintf(v.z * inv);
                o[p * 4 + 3] = (int8_t)(int)rintf(v.w * inv);
            }
            const size_t slab = (size_t)(((bm * 64 + k0) * 2 + wm) * 4 + islab);
            *(i32x4*)(Xs + slab * 1024 + (quad * 16 + r) * 16) = *(i32x4*)o;
        }
        return;
    }
    b -= BLK_X;

    if (b < BLK_W) {
        // ---- role W ----
        const int n0 = b * 16;
        const int r = tid >> 4, u = tid & 15;
        const int* qrow = qw + (size_t)(n0 + r) * Kdim + u * 256;
        const int bn = b >> 3, wn = (b >> 2) & 1, jslab = b & 3;
#pragma unroll 4
        for (int j = 0; j < 16; ++j) {
            const int c = u * 16 + j;
            const int k0 = c >> 2, quad = c & 3;
            const int4* q4 = (const int4*)(qrow + j * 16);
            int4 q0 = q4[0], q1 = q4[1], q2 = q4[2], q3 = q4[3];
            int8_t o[16] = {(int8_t)q0.x, (int8_t)q0.y, (int8_t)q0.z, (int8_t)q0.w,
                            (int8_t)q1.x, (int8_t)q1.y, (int8_t)q1.z, (int8_t)q1.w,
                            (int8_t)q2.x, (int8_t)q2.y, (int8_t)q2.z, (int8_t)q2.w,
                            (int8_t)q3.x, (int8_t)q3.y, (int8_t)q3.z, (int8_t)q3.w};
            const size_t slab = (size_t)(((bn * 64 + k0) * 2 + wn) * 4 + jslab);
            *(i32x4*)(Bs + slab * 1024 + (quad * 16 + r) * 16) = *(i32x4*)o;
        }
        return;
    }
    b -= BLK_W;

    if (b == 0) {
        // ---- role A: global absmax + quantize to B-operand frag layout ----
        float am = 0.f;
        const float4* ap = (const float4*)lA + tid * 64;  // 256 floats/thread
        for (int q = 0; q < 64; ++q) {
            float4 v = ap[q];
            am = fmaxf(am, fmaxf(fmaxf(fabsf(v.x), fabsf(v.y)),
                                 fmaxf(fabsf(v.z), fabsf(v.w))));
        }
#pragma unroll
        for (int off = 1; off < 64; off <<= 1) am = fmaxf(am, __shfl_xor(am, off));
        if ((tid & 63) == 0) red[tid >> 6] = am;
        __syncthreads();
        const float amax = fmaxf(fmaxf(red[0], red[1]), fmaxf(red[2], red[3]));
        if (tid == 0) a_scale_g[0] = amax > 0.f ? amax / 127.f : 0.f;
        const float inv = amax > 0.f ? 127.f / amax : 0.f;
        const int rho = tid & 15, u = tid >> 4;
        for (int j = 0; j < 16; ++j) {
            const int c = u * 16 + j;          // k-chunk 0..255
            const int k0 = c >> 2, quad = c & 3;
            int8_t o[16];
#pragma unroll
            for (int kk = 0; kk < 16; ++kk)
                o[kk] = (int8_t)(int)rintf(lA[(size_t)(c * 16 + kk) * 16 + rho] * inv);
            *(i32x4*)(a_i8 + (size_t)k0 * 1024 + (quad * 16 + rho) * 16) = *(i32x4*)o;
        }
        return;
    }
    b -= 1;

    {
        // ---- role Bt ----
        const int c = b * 256 + tid;
        __bf16 tmp[16];
#pragma unroll
        for (int rr = 0; rr < 16; ++rr) tmp[rr] = (__bf16)lB[(size_t)rr * Ndim + c];
        *(bf16x8*)(Blbt + (size_t)c * 16) = *(bf16x8*)tmp;
        *(bf16x8*)(Blbt + (size_t)c * 16 + 8) = *(bf16x8*)(tmp + 8);
    }
}

// ---------------- xA = x_i8 @ A_i8^T -> bf16 [M][16], no LDS ----------------
__global__ void __launch_bounds__(256) xa_kernel(
        const int8_t* __restrict__ Xs,
        const int8_t* __restrict__ a_i8,
        const float* __restrict__ row_scale,
        const float* __restrict__ a_scale_g,
        __bf16* __restrict__ xab) {
    const int tid = threadIdx.x, wave = tid >> 6, lane = tid & 63;
    const int quad = lane >> 4, l16 = lane & 15;
    const int bm2 = blockIdx.x;              // 64 rows per block
    const int bm = bm2 >> 1, wm = bm2 & 1;
    const int8_t* aptr = Xs + (size_t)((bm * 64 * 2 + wm) * 4 + wave) * 1024 + lane * 16;
    const int8_t* bptr = a_i8 + lane * 16;
    i32x4 acc = {0, 0, 0, 0};
#pragma unroll 4
    for (int k0 = 0; k0 < 64; ++k0) {
        i32x4 af = *(const i32x4*)(aptr + (size_t)k0 * 8192);
        i32x4 bf = *(const i32x4*)(bptr + (size_t)k0 * 1024);
        acc = __builtin_amdgcn_mfma_i32_16x16x64_i8(af, bf, acc, 0, 0, 0);
    }
    const float asc = a_scale_g[0];
    const int rl = wave * 16 + quad * 4;
#pragma unroll
    for (int r = 0; r < 4; ++r) {
        const int grow = bm2 * 64 + rl + r;
        float v = (float)acc[r] * row_scale[grow] * asc;
        xab[(size_t)grow * 16 + l16] = (__bf16)v;
    }
}

// ---------------- main GEMM: no LDS, no barriers in K-loop ----------------
__global__ void __launch_bounds__(256) gemm_flat(
        const int8_t* __restrict__ Xs,     // frag layout
        const int8_t* __restrict__ Bs,     // frag layout
        const float* __restrict__ scales,
        const float* __restrict__ bias,
        const float* __restrict__ row_scale,
        const __bf16* __restrict__ xab,    // [M][16]
        const __bf16* __restrict__ Blbt,   // [N][16]
        float* __restrict__ out) {
    __shared__ __align__(16) char smem[8704];

    const int tid = threadIdx.x, wave = tid >> 6, lane = tid & 63;
    const int wm = wave >> 1, wn = wave & 1;
    const int quad = lane >> 4, l16 = lane & 15;
    const int bm = blockIdx.y, bn = blockIdx.x;

    const int8_t* aptr = Xs + (size_t)((bm * 64 * 2 + wm) * 4) * 1024 + lane * 16;
    const int8_t* bptr = Bs + (size_t)((bn * 64 * 2 + wn) * 4) * 1024 + lane * 16;

    i32x4 acc[4][4];
#pragma unroll
    for (int i = 0; i < 4; ++i)
#pragma unroll
        for (int j = 0; j < 4; ++j) acc[i][j] = i32x4{0, 0, 0, 0};

#pragma unroll 2
    for (int k0 = 0; k0 < 64; ++k0) {
        i32x4 aF[4], bF[4];
#pragma unroll
        for (int i = 0; i < 4; ++i)
            aF[i] = *(const i32x4*)(aptr + (size_t)k0 * 8192 + i * 1024);
#pragma unroll
        for (int j = 0; j < 4; ++j)
            bF[j] = *(const i32x4*)(bptr + (size_t)k0 * 8192 + j * 1024);
#pragma unroll
        for (int i = 0; i < 4; ++i)
#pragma unroll
            for (int j = 0; j < 4; ++j)
                acc[i][j] = __builtin_amdgcn_mfma_i32_16x16x64_i8(aF[i], bF[j], acc[i][j], 0, 0, 0);
    }

    // -------- epilogue: lora bf16 MFMA (K=16 zero-padded) + bias + dequant --------
    const float wsc = scales[0];
    float bj4[4];
#pragma unroll
    for (int j = 0; j < 4; ++j) bj4[j] = bias[bn * 128 + wn * 64 + j * 16 + l16];

    async_copy16((const char*)(xab + (size_t)bm * 128 * 16) + tid * 16, smem + tid * 16);
    async_copy16((const char*)(Blbt + (size_t)bn * 128 * 16) + tid * 16, smem + 4096 + tid * 16);
    if (tid < 32)
        async_copy16((const char*)(row_scale + bm * 128) + tid * 16, smem + 8192 + tid * 16);
    __syncthreads();

    const __bf16* sXA = (const __bf16*)smem;          // [128][16]
    const __bf16* sBL = (const __bf16*)(smem + 4096); // [128 cols][16]
    const float*  sRS = (const float*)(smem + 8192);  // [128]

    bf16x8 zf;
#pragma unroll
    for (int k = 0; k < 8; ++k) zf[k] = (__bf16)0.f;

    bf16x8 aF2[4], bF2[4];
#pragma unroll
    for (int i = 0; i < 4; ++i) {
        if (quad < 2) aF2[i] = *(const bf16x8*)(sXA + (wm * 64 + i * 16 + l16) * 16 + quad * 8);
        else          aF2[i] = zf;
    }
#pragma unroll
    for (int j = 0; j < 4; ++j) {
        if (quad < 2) bF2[j] = *(const bf16x8*)(sBL + (wn * 64 + j * 16 + l16) * 16 + quad * 8);
        else          bF2[j] = zf;
    }

    f32x4 lacc[4][4];
#pragma unroll
    for (int j = 0; j < 4; ++j)
#pragma unroll
        for (int i = 0; i < 4; ++i)
            lacc[i][j] = f32x4{bj4[j], bj4[j], bj4[j], bj4[j]};

#pragma unroll
    for (int i = 0; i < 4; ++i)
#pragma unroll
        for (int j = 0; j < 4; ++j)
            lacc[i][j] = __builtin_amdgcn_mfma_f32_16x16x32_bf16(aF2[i], bF2[j], lacc[i][j], 0, 0, 0);

    const int col0 = bn * 128 + wn * 64 + l16;
    const int rl0 = wm * 64 + quad * 4;
#pragma unroll
    for (int j = 0; j < 4; ++j) {
        const int col = col0 + j * 16;
#pragma unroll
        for (int i = 0; i < 4; ++i) {
            const int lr = rl0 + i * 16;
#pragma unroll
            for (int r = 0; r < 4; ++r) {
                const float sx = sRS[lr + r] * wsc;
                out[(size_t)(bm * 128 + lr + r) * Ndim + col] =
                    (float)acc[i][j][r] * sx + lacc[i][j][r];
            }
        }
    }
}

extern "C" void kernel_launch(void* const* d_in, const int* in_sizes, int n_in,
                              void* d_out, int out_size, void* d_ws, size_t ws_size,
                              hipStream_t stream) {
    const float* x      = (const float*)d_in[0];
    const int*   qw     = (const int*)d_in[1];
    const float* scales = (const float*)d_in[2];
    const float* bias   = (const float*)d_in[3];
    const float* lA     = (const float*)d_in[4];
    const float* lB     = (const float*)d_in[5];
    float* out = (float*)d_out;

    char* ws = (char*)d_ws;
    int8_t* Xs     = (int8_t*)ws;                               // 33.55 MB
    int8_t* Bs     = (int8_t*)(ws + 33554432);                  // 16.78 MB
    int8_t* a_i8   = (int8_t*)(ws + 50331648);                  // 64 KB
    __bf16* xab    = (__bf16*)(ws + 50397184);                  // 256 KB
    __bf16* Blbt   = (__bf16*)(ws + 50659328);                  // 128 KB
    float* row_scale = (float*)(ws + 50790400);                 // 32 KB
    float* a_scale_g = (float*)(ws + 50823168);                 // 4 B

    const int prep_blocks = BLK_X + BLK_W + 1 + BLK_BT;         // 785
    prep_kernel<<<prep_blocks, 256, 0, stream>>>(
        x, qw, lA, lB, Xs, Bs, a_i8, Blbt, row_scale, a_scale_g);
    xa_kernel<<<Mdim / 64, 256, 0, stream>>>(Xs, a_i8, row_scale, a_scale_g, xab);
    dim3 grid(Ndim / 128, Mdim / 128);
    gemm_flat<<<grid, 256, 0, stream>>>(Xs, Bs, scales, bias, row_scale,
                                        xab, Blbt, out);
}